// Round 6
// baseline (286.396 us; speedup 1.0000x reference)
//
#include <hip/hip_runtime.h>

// ---------------------------------------------------------------------------
// CausalSelfAttention: y = proj(attn(qkv(x)))  B=4 T=2048 E=1024 H=16 D=64
// Mask: rows<512 attend cols<512 (full); rows>=512 causal.
// R12: attn wave-tile widening. R11 floor analysis: LDS-read pipe ~23us was
//     the largest attn component (72.7K wave-tiles x 24 ds_reads each),
//     scaling with wave-tile COUNT not work. Wave now owns 64 q-rows
//     (mi=0..3): K/V fragments read once feed 2x MFMAs -> LDS-read cycles
//     per unit work halve; addr VALU halves; MFMA/exp conserved. Blocks =
//     256 q-rows x 4 waves; grid 64x8 = 512 = 2/CU (VGPR ~190 -> 2/SIMD).
//     Slot order {7,6,5,4,0,1,2,3} balances per-CU tile sums (40/36/36/36).
//     Near-diagonal tiles skip inactive mi (wave-uniform guards; barriers
//     outside guards). Staging/dbuf/swizzles/softmax identical to R11.
//     qkv/proj/prep unchanged (qkv at m97-structure K=1024 ceiling; 8-phase
//     port is the next candidate).
// ---------------------------------------------------------------------------

typedef _Float16 f16;
typedef _Float16 f16x4 __attribute__((ext_vector_type(4)));
typedef _Float16 f16x8 __attribute__((ext_vector_type(8)));
typedef float f32x4 __attribute__((ext_vector_type(4)));

#define MFMA16x32(a, b, c) __builtin_amdgcn_mfma_f32_16x16x32_f16(a, b, c, 0, 0, 0)
#define MFMA16x16(a, b, c) __builtin_amdgcn_mfma_f32_16x16x16f16(a, b, c, 0, 0, 0)

__device__ __forceinline__ void gload_lds16(const void* g, void* l) {
  __builtin_amdgcn_global_load_lds(
      (__attribute__((address_space(1))) void*)g,
      (__attribute__((address_space(3))) void*)l, 16, 0, 0);
}

// --------------------------- prep: cast + transposes (one launch) ----------

__global__ __launch_bounds__(256) void k_prep(
    const float* __restrict__ x, f16* __restrict__ xh,
    const float* __restrict__ Wq, f16* __restrict__ Wqt,
    const float* __restrict__ Wp, f16* __restrict__ Wpt) {
  __shared__ float tile[32][33];
  const int bid = blockIdx.x;
  if (bid < 8192) {
    int i = bid * 256 + threadIdx.x;
    float4 v = ((const float4*)x)[i];
    f16x4 o = {(f16)v.x, (f16)v.y, (f16)v.z, (f16)v.w};
    ((f16x4*)xh)[i] = o;
    return;
  }
  const float* W;
  f16* Wt;
  int Ndim, bx, by;
  if (bid < 8192 + 3072) {
    int r = bid - 8192;
    W = Wq; Wt = Wqt; Ndim = 3072; bx = r % 96; by = r / 96;
  } else {
    int r = bid - 11264;
    W = Wp; Wt = Wpt; Ndim = 1024; bx = r % 32; by = r / 32;
  }
  const int tx = threadIdx.x & 31, ty = threadIdx.x >> 5;
  const int n = bx * 32 + tx;
  const int k0 = by * 32;
  for (int j = ty; j < 32; j += 8)
    tile[j][tx] = W[(size_t)(k0 + j) * Ndim + n];
  __syncthreads();
  const int k = k0 + tx;
  for (int j = ty; j < 32; j += 8)
    Wt[(size_t)(bx * 32 + j) * 1024 + k] = (f16)tile[tx][j];
}

// --------------------------- GEMM1: x @ W_qkv -------------------------------

__global__ __launch_bounds__(256) void k_gemm_qkv(
    const f16* __restrict__ A, const f16* __restrict__ Bt,
    const float* __restrict__ bias,
    f16* __restrict__ Qo, f16* __restrict__ Ko, f16* __restrict__ Vo) {
  constexpr int KD = 1024;
  __shared__ __align__(16) f16 smem[2 * 128 * 64];  // As | Bs; Es aliased
  f16* As = smem;
  f16* Bs = smem + 128 * 64;
  const int tid = threadIdx.x;
  const int wave = tid >> 6, lane = tid & 63;
  const int g = lane >> 4, l16 = lane & 15;
  const int m0 = blockIdx.y * 128, n0 = blockIdx.x * 128;
  const int wm = (wave >> 1) * 64, wn = (wave & 1) * 64;
  const int srow = wave * 8 + (lane >> 3);          // staging row in 32-group
  const int skc = ((lane & 7) ^ (lane >> 3)) * 8;   // pre-swizzled src chunk

  f32x4 acc[4][4] = {};

  for (int k0 = 0; k0 < KD; k0 += 64) {
    __syncthreads();
    for (int it = 0; it < 4; ++it) {
      gload_lds16(A + (size_t)(m0 + it * 32 + srow) * KD + k0 + skc,
                  As + (it * 32 + wave * 8) * 64);
      gload_lds16(Bt + (size_t)(n0 + it * 32 + srow) * KD + k0 + skc,
                  Bs + (it * 32 + wave * 8) * 64);
    }
    __syncthreads();
    for (int kk = 0; kk < 64; kk += 32) {
      const int ks = kk >> 3;  // chunk slot base: 0 or 4
      f16x8 af[4], bf[4];
      for (int mi = 0; mi < 4; ++mi) {
        int R = wm + mi * 16 + l16, sw = R & 7;
        af[mi] = *(const f16x8*)(As + R * 64 + ((ks + g) ^ sw) * 8);
      }
      for (int ni = 0; ni < 4; ++ni) {
        int R = wn + ni * 16 + l16, sw = R & 7;
        bf[ni] = *(const f16x8*)(Bs + R * 64 + ((ks + g) ^ sw) * 8);
      }
      for (int mi = 0; mi < 4; ++mi)
        for (int ni = 0; ni < 4; ++ni)
          acc[mi][ni] = MFMA16x32(af[mi], bf[ni], acc[mi][ni]);
    }
  }

  // ---- epilogue: per-wave 64x64 swizzled stage (aliased over As/Bs) ----
  const int nsub = n0 + wn;            // multiple of 64 -> one (part, head)
  const int part = nsub >> 10;         // 0=Q 1=K 2=V
  const int h    = (nsub >> 6) & 15;
  const int mg   = m0 + wm;
  const int b    = mg >> 11;
  const int tb   = mg & 2047;
  const size_t bh = (size_t)(b * 16 + h);

  float bv[4];
  for (int ni = 0; ni < 4; ++ni) bv[ni] = bias[nsub + ni * 16 + l16];

  __syncthreads();  // all fragment reads of As/Bs complete before overwrite
  f16* Es = smem + wave * 4096;  // 64x64, chunk-XOR swizzled by row&7

  for (int mi = 0; mi < 4; ++mi)
    for (int ni = 0; ni < 4; ++ni)
      for (int r = 0; r < 4; ++r) {
        f16 hv = (f16)(acc[mi][ni][r] + bv[ni]);
        int mrow = mi * 16 + g * 4 + r, ncol = ni * 16 + l16;
        if (part == 2)  // store transposed: [d][t]
          Es[ncol * 64 + (mrow ^ ((ncol & 7) << 3))] = hv;
        else            // [t][d]
          Es[mrow * 64 + (ncol ^ ((mrow & 7) << 3))] = hv;
      }
  // same-wave DS write->read: LDS pipe in-order, no barrier needed

  const int rrow = lane >> 3, rj = lane & 7;
  for (int p = 0; p < 8; ++p) {
    int row = p * 8 + rrow;
    f16x8 vv = *(const f16x8*)(Es + row * 64 + (rj ^ (row & 7)) * 8);
    int rcol = rj * 8;
    if (part == 0)
      *(f16x8*)(Qo + (bh * 2048 + tb + row) * 64 + rcol) = vv;
    else if (part == 1)
      *(f16x8*)(Ko + (bh * 2048 + tb + row) * 64 + rcol) = vv;
    else  // row is d, rcol is t-offset
      *(f16x8*)(Vo + (bh * 64 + row) * 2048 + tb + rcol) = vv;
  }
}

// --------------------------- flash attention (64 q-rows / wave) -------------
// grid (64 bh, 8 slots); block 256 = 4 waves; wave owns 64 q-rows (mi 0..3).
// Slot -> 256-row q-block qb via {7,6,5,4,0,1,2,3} (pairs CU load to
// 40/36/36/36 tiles under c%256 round-robin). nt = qb<2 ? 8 : 4(qb+1).
// K/V frags read once per tile feed 4 mi -> half the LDS-read issue of R11.
// Inactive mi near the diagonal skipped with wave-uniform guards.

__global__ __launch_bounds__(256, 2) void k_attn(
    const f16* __restrict__ Q, const f16* __restrict__ Kb,
    const f16* __restrict__ Vt, f16* __restrict__ Y) {
  __shared__ __align__(16) f16 Ks[2][64 * 64];
  __shared__ __align__(16) f16 Vs[2][64 * 64];
  __shared__ float rs[4 * 64];  // per-wave row sums

  const int tid = threadIdx.x;
  const int wave = tid >> 6, lane = tid & 63;
  const int g = lane >> 4, l16 = lane & 15;
  const int bh = blockIdx.x;
  const int b = bh >> 4, h = bh & 15;
  const int by = blockIdx.y;
  const int qb = (by < 4) ? (7 - by) : (by - 4);   // 256-row q-block
  const int q0 = qb * 256;
  const int nt = (qb < 2) ? 8 : 4 * (qb + 1);      // k-tiles (64 each)
  const int qw = q0 + wave * 64;                   // wave's first q row
  const bool causal = (q0 >= 512);
  const int srowrel = lane >> 3;
  const int sc = (lane & 7) ^ srowrel;  // XOR-swizzled staging chunk

  const f32x4 sinit = {-8.65617025f, -8.65617025f, -8.65617025f, -8.65617025f};

  // Q B-fragments (operand-swapped QK), pre-scaled by log2(e)/8
  f16x8 aq[4][2];
  for (int mi = 0; mi < 4; ++mi) {
    const f16* qrow =
        Q + ((size_t)bh * 2048 + qw + mi * 16 + l16) * 64 + g * 8;
    aq[mi][0] = *(const f16x8*)(qrow);
    aq[mi][1] = *(const f16x8*)(qrow + 32);
    for (int kb = 0; kb < 2; ++kb)
      aq[mi][kb] = aq[mi][kb] * (f16)0.18033688f;
  }

  f32x4 o[4][4] = {};       // o[mi][db]: O[row mi*16+g*4+r][d=db*16+l16]
  float rsum[4] = {};       // per-lane partial for row mi*16+l16

  // prologue: stage tile 0 into buf 0 (each wave: 16 K rows + 16 V rows)
  for (int it = 0; it < 2; ++it) {
    int row = it * 32 + wave * 8 + srowrel;
    gload_lds16(Kb + ((size_t)bh * 2048 + row) * 64 + sc * 8,
                &Ks[0][(it * 32 + wave * 8) * 64]);
    gload_lds16(Vt + ((size_t)bh * 64 + row) * 2048 + sc * 8,
                &Vs[0][(it * 32 + wave * 8) * 64]);
  }
  __syncthreads();

  int cur = 0;
  for (int i = 0; i < nt; ++i) {
    // ---- stage tile i+1 into buf cur^1 (readers joined at barrier i-1) ----
    if (i + 1 < nt) {
      const int kn0 = (i + 1) << 6;
      for (int it = 0; it < 2; ++it) {
        int row = it * 32 + wave * 8 + srowrel;
        gload_lds16(Kb + ((size_t)bh * 2048 + kn0 + row) * 64 + sc * 8,
                    &Ks[cur ^ 1][(it * 32 + wave * 8) * 64]);
        gload_lds16(Vt + ((size_t)bh * 64 + row) * 2048 + kn0 + sc * 8,
                    &Vs[cur ^ 1][(it * 32 + wave * 8) * 64]);
      }
    }

    // ---- compute tile i from buf cur ----
    const int kt0 = i << 6;
    const f16* Kc = Ks[cur];
    const f16* Vc = Vs[cur];

    // per-mi activity (wave-uniform): rows qw+mi*16.. see cols <= kt0+63?
    bool act[4];
    for (int mi = 0; mi < 4; ++mi)
      act[mi] = !causal || (kt0 <= qw + mi * 16 + 15);

    // K fragments once per tile (feed all 4 mi)
    f16x8 bk0[4], bk1[4];
    for (int nb = 0; nb < 4; ++nb) {
      int R = nb * 16 + l16, sw = R & 7;
      bk0[nb] = *(const f16x8*)(Kc + R * 64 + ((0 + g) ^ sw) * 8);
      bk1[nb] = *(const f16x8*)(Kc + R * 64 + ((4 + g) ^ sw) * 8);
    }

    // T = K Q^T per mi -> exp -> P in registers as 16x16x16 A-frags
    f16x4 ap[4][4];  // [mi][nb]
    for (int mi = 0; mi < 4; ++mi) {
      if (!act[mi]) continue;
      f32x4 t[4];
      for (int nb = 0; nb < 4; ++nb) {
        f32x4 acc = MFMA16x32(bk0[nb], aq[mi][0], sinit);
        t[nb] = MFMA16x32(bk1[nb], aq[mi][1], acc);
      }
      const int mbase = qw + mi * 16;
      const bool masked = causal && (kt0 + 63 > mbase);
      const int mrow = mbase + l16;
      for (int nb = 0; nb < 4; ++nb)
        for (int r = 0; r < 4; ++r) {
          float pv = __builtin_amdgcn_exp2f(t[nb][r]);
          if (masked && (kt0 + nb * 16 + g * 4 + r > mrow)) pv = 0.f;
          rsum[mi] += pv;
          ap[mi][nb][r] = (f16)pv;
        }
    }

    // O += P V : V^T b64 frags read once feed all 4 mi
    for (int db = 0; db < 4; ++db)
      for (int nb = 0; nb < 4; ++nb) {
        int R = db * 16 + l16, sw = R & 7;
        int c = nb * 2 + (g >> 1);
        f16x4 bv = *(const f16x4*)(Vc + R * 64 + (c ^ sw) * 8 + (g & 1) * 4);
        for (int mi = 0; mi < 4; ++mi)
          if (act[mi]) o[mi][db] = MFMA16x16(ap[mi][nb], bv, o[mi][db]);
      }

    __syncthreads();  // joins all waves' reads of buf cur + drains stages
    cur ^= 1;
  }

  // reduce rsum across quads: all lanes with same l16 get the row total
  for (int mi = 0; mi < 4; ++mi) {
    rsum[mi] += __shfl_xor(rsum[mi], 16, 64);
    rsum[mi] += __shfl_xor(rsum[mi], 32, 64);
  }

  // broadcast row totals to the lanes that hold O rows g*4+r (via LDS)
  if (g == 0)
    for (int mi = 0; mi < 4; ++mi) rs[wave * 64 + mi * 16 + l16] = rsum[mi];
  // same-wave DS write->read: LDS pipe in-order, no barrier needed
  float rinv[4][4];
  for (int mi = 0; mi < 4; ++mi)
    for (int r = 0; r < 4; ++r)
      rinv[mi][r] = 1.0f / rs[wave * 64 + mi * 16 + g * 4 + r];

  // normalize -> f16 -> direct stores (L2 merges 32B segments)
  const size_t ybase = (size_t)b * 2048 + qw;
  for (int mi = 0; mi < 4; ++mi)
    for (int db = 0; db < 4; ++db)
      for (int r = 0; r < 4; ++r)
        Y[(ybase + mi * 16 + g * 4 + r) * 1024 + h * 64 + db * 16 + l16] =
            (f16)(o[mi][db][r] * rinv[mi][r]);
}

// --------------------------- GEMM2: y @ W_proj ------------------------------

__global__ __launch_bounds__(256) void k_gemm_proj(
    const f16* __restrict__ A, const f16* __restrict__ Bt,
    const float* __restrict__ bias, float* __restrict__ out) {
  constexpr int KD = 1024;
  __shared__ __align__(16) f16 As[128 * 64];
  __shared__ __align__(16) f16 Bs[128 * 64];
  const int tid = threadIdx.x;
  const int wave = tid >> 6, lane = tid & 63;
  const int g = lane >> 4, l16 = lane & 15;
  const int m0 = blockIdx.y * 128, n0 = blockIdx.x * 128;
  const int wm = (wave >> 1) * 64, wn = (wave & 1) * 64;
  const int srow = wave * 8 + (lane >> 3);
  const int skc = ((lane & 7) ^ (lane >> 3)) * 8;   // pre-swizzled src chunk

  f32x4 acc[4][4] = {};

  for (int k0 = 0; k0 < KD; k0 += 64) {
    __syncthreads();
    for (int it = 0; it < 4; ++it) {
      gload_lds16(A + (size_t)(m0 + it * 32 + srow) * KD + k0 + skc,
                  As + (it * 32 + wave * 8) * 64);
      gload_lds16(Bt + (size_t)(n0 + it * 32 + srow) * KD + k0 + skc,
                  Bs + (it * 32 + wave * 8) * 64);
    }
    __syncthreads();
    for (int kk = 0; kk < 64; kk += 32) {
      const int ks = kk >> 3;
      f16x8 af[4], bf[4];
      for (int mi = 0; mi < 4; ++mi) {
        int R = wm + mi * 16 + l16, sw = R & 7;
        af[mi] = *(const f16x8*)(As + R * 64 + ((ks + g) ^ sw) * 8);
      }
      for (int ni = 0; ni < 4; ++ni) {
        int R = wn + ni * 16 + l16, sw = R & 7;
        bf[ni] = *(const f16x8*)(Bs + R * 64 + ((ks + g) ^ sw) * 8);
      }
      for (int mi = 0; mi < 4; ++mi)
        for (int ni = 0; ni < 4; ++ni)
          acc[mi][ni] = MFMA16x32(af[mi], bf[ni], acc[mi][ni]);
    }
  }

  float bv[4];
  for (int ni = 0; ni < 4; ++ni) bv[ni] = bias[n0 + wn + ni * 16 + l16];

  for (int mi = 0; mi < 4; ++mi)
    for (int ni = 0; ni < 4; ++ni)
      for (int r = 0; r < 4; ++r) {
        int m = m0 + wm + mi * 16 + g * 4 + r;
        int n = n0 + wn + ni * 16 + l16;
        out[(size_t)m * 1024 + n] = acc[mi][ni][r] + bv[ni];
      }
}

// --------------------------- launch ----------------------------------------

extern "C" void kernel_launch(void* const* d_in, const int* in_sizes, int n_in,
                              void* d_out, int out_size, void* d_ws,
                              size_t ws_size, hipStream_t stream) {
  const float* x      = (const float*)d_in[0];
  const float* W_qkv  = (const float*)d_in[1];
  const float* b_qkv  = (const float*)d_in[2];
  const float* W_proj = (const float*)d_in[3];
  const float* b_proj = (const float*)d_in[4];
  float* out = (float*)d_out;

  char* ws = (char*)d_ws;
  f16* xh    = (f16*)ws;   ws += (size_t)8192 * 1024 * 2;   // also reused as Y
  f16* Wqt   = (f16*)ws;   ws += (size_t)3072 * 1024 * 2;
  f16* Wpt   = (f16*)ws;   ws += (size_t)1024 * 1024 * 2;
  f16* Qb    = (f16*)ws;   ws += (size_t)64 * 2048 * 64 * 2;
  f16* Kb    = (f16*)ws;   ws += (size_t)64 * 2048 * 64 * 2;
  f16* Vt    = (f16*)ws;   ws += (size_t)64 * 64 * 2048 * 2;
  f16* Y = xh;  // xh fully consumed by k_gemm_qkv before k_attn writes Y

  k_prep<<<12288, 256, 0, stream>>>(x, xh, W_qkv, Wqt, W_proj, Wpt);
  k_gemm_qkv<<<dim3(24, 64), 256, 0, stream>>>(xh, Wqt, b_qkv, Qb, Kb, Vt);
  k_attn<<<dim3(64, 8), 256, 0, stream>>>(Qb, Kb, Vt, Y);
  k_gemm_proj<<<dim3(8, 64), 256, 0, stream>>>(Y, Wpt, b_proj, out);
}

// Round 7
// 254.192 us; speedup vs baseline: 1.1267x; 1.1267x over previous
//
#include <hip/hip_runtime.h>

// ---------------------------------------------------------------------------
// CausalSelfAttention: y = proj(attn(qkv(x)))  B=4 T=2048 E=1024 H=16 D=64
// Mask: rows<512 attend cols<512 (full); rows>=512 causal.
// R13: revert R12 (64-row waves: VGPR 120 -> 2 blocks/CU, Occ 13.5%, attn
//     75->102us; occupancy dominates per-wave efficiency in this family).
//     Back to R11's attn (32-row waves, 4 blocks/CU, 1024 blocks) + T5
//     s_setprio(1) around QK/PV MFMA clusters: attn blocks are independent
//     (phase-diverse waves/CU) = m191's +4-7% regime, not m190's lockstep
//     null. qkv/proj/prep identical to R11.
// ---------------------------------------------------------------------------

typedef _Float16 f16;
typedef _Float16 f16x4 __attribute__((ext_vector_type(4)));
typedef _Float16 f16x8 __attribute__((ext_vector_type(8)));
typedef float f32x4 __attribute__((ext_vector_type(4)));

#define MFMA16x32(a, b, c) __builtin_amdgcn_mfma_f32_16x16x32_f16(a, b, c, 0, 0, 0)
#define MFMA16x16(a, b, c) __builtin_amdgcn_mfma_f32_16x16x16f16(a, b, c, 0, 0, 0)

__device__ __forceinline__ void gload_lds16(const void* g, void* l) {
  __builtin_amdgcn_global_load_lds(
      (__attribute__((address_space(1))) void*)g,
      (__attribute__((address_space(3))) void*)l, 16, 0, 0);
}

// --------------------------- prep: cast + transposes (one launch) ----------

__global__ __launch_bounds__(256) void k_prep(
    const float* __restrict__ x, f16* __restrict__ xh,
    const float* __restrict__ Wq, f16* __restrict__ Wqt,
    const float* __restrict__ Wp, f16* __restrict__ Wpt) {
  __shared__ float tile[32][33];
  const int bid = blockIdx.x;
  if (bid < 8192) {
    int i = bid * 256 + threadIdx.x;
    float4 v = ((const float4*)x)[i];
    f16x4 o = {(f16)v.x, (f16)v.y, (f16)v.z, (f16)v.w};
    ((f16x4*)xh)[i] = o;
    return;
  }
  const float* W;
  f16* Wt;
  int Ndim, bx, by;
  if (bid < 8192 + 3072) {
    int r = bid - 8192;
    W = Wq; Wt = Wqt; Ndim = 3072; bx = r % 96; by = r / 96;
  } else {
    int r = bid - 11264;
    W = Wp; Wt = Wpt; Ndim = 1024; bx = r % 32; by = r / 32;
  }
  const int tx = threadIdx.x & 31, ty = threadIdx.x >> 5;
  const int n = bx * 32 + tx;
  const int k0 = by * 32;
  for (int j = ty; j < 32; j += 8)
    tile[j][tx] = W[(size_t)(k0 + j) * Ndim + n];
  __syncthreads();
  const int k = k0 + tx;
  for (int j = ty; j < 32; j += 8)
    Wt[(size_t)(bx * 32 + j) * 1024 + k] = (f16)tile[tx][j];
}

// --------------------------- GEMM1: x @ W_qkv -------------------------------

__global__ __launch_bounds__(256) void k_gemm_qkv(
    const f16* __restrict__ A, const f16* __restrict__ Bt,
    const float* __restrict__ bias,
    f16* __restrict__ Qo, f16* __restrict__ Ko, f16* __restrict__ Vo) {
  constexpr int KD = 1024;
  __shared__ __align__(16) f16 smem[2 * 128 * 64];  // As | Bs; Es aliased
  f16* As = smem;
  f16* Bs = smem + 128 * 64;
  const int tid = threadIdx.x;
  const int wave = tid >> 6, lane = tid & 63;
  const int g = lane >> 4, l16 = lane & 15;
  const int m0 = blockIdx.y * 128, n0 = blockIdx.x * 128;
  const int wm = (wave >> 1) * 64, wn = (wave & 1) * 64;
  const int srow = wave * 8 + (lane >> 3);          // staging row in 32-group
  const int skc = ((lane & 7) ^ (lane >> 3)) * 8;   // pre-swizzled src chunk

  f32x4 acc[4][4] = {};

  for (int k0 = 0; k0 < KD; k0 += 64) {
    __syncthreads();
    for (int it = 0; it < 4; ++it) {
      gload_lds16(A + (size_t)(m0 + it * 32 + srow) * KD + k0 + skc,
                  As + (it * 32 + wave * 8) * 64);
      gload_lds16(Bt + (size_t)(n0 + it * 32 + srow) * KD + k0 + skc,
                  Bs + (it * 32 + wave * 8) * 64);
    }
    __syncthreads();
    for (int kk = 0; kk < 64; kk += 32) {
      const int ks = kk >> 3;  // chunk slot base: 0 or 4
      f16x8 af[4], bf[4];
      for (int mi = 0; mi < 4; ++mi) {
        int R = wm + mi * 16 + l16, sw = R & 7;
        af[mi] = *(const f16x8*)(As + R * 64 + ((ks + g) ^ sw) * 8);
      }
      for (int ni = 0; ni < 4; ++ni) {
        int R = wn + ni * 16 + l16, sw = R & 7;
        bf[ni] = *(const f16x8*)(Bs + R * 64 + ((ks + g) ^ sw) * 8);
      }
      for (int mi = 0; mi < 4; ++mi)
        for (int ni = 0; ni < 4; ++ni)
          acc[mi][ni] = MFMA16x32(af[mi], bf[ni], acc[mi][ni]);
    }
  }

  // ---- epilogue: per-wave 64x64 swizzled stage (aliased over As/Bs) ----
  const int nsub = n0 + wn;            // multiple of 64 -> one (part, head)
  const int part = nsub >> 10;         // 0=Q 1=K 2=V
  const int h    = (nsub >> 6) & 15;
  const int mg   = m0 + wm;
  const int b    = mg >> 11;
  const int tb   = mg & 2047;
  const size_t bh = (size_t)(b * 16 + h);

  float bv[4];
  for (int ni = 0; ni < 4; ++ni) bv[ni] = bias[nsub + ni * 16 + l16];

  __syncthreads();  // all fragment reads of As/Bs complete before overwrite
  f16* Es = smem + wave * 4096;  // 64x64, chunk-XOR swizzled by row&7

  for (int mi = 0; mi < 4; ++mi)
    for (int ni = 0; ni < 4; ++ni)
      for (int r = 0; r < 4; ++r) {
        f16 hv = (f16)(acc[mi][ni][r] + bv[ni]);
        int mrow = mi * 16 + g * 4 + r, ncol = ni * 16 + l16;
        if (part == 2)  // store transposed: [d][t]
          Es[ncol * 64 + (mrow ^ ((ncol & 7) << 3))] = hv;
        else            // [t][d]
          Es[mrow * 64 + (ncol ^ ((mrow & 7) << 3))] = hv;
      }
  // same-wave DS write->read: LDS pipe in-order, no barrier needed

  const int rrow = lane >> 3, rj = lane & 7;
  for (int p = 0; p < 8; ++p) {
    int row = p * 8 + rrow;
    f16x8 vv = *(const f16x8*)(Es + row * 64 + (rj ^ (row & 7)) * 8);
    int rcol = rj * 8;
    if (part == 0)
      *(f16x8*)(Qo + (bh * 2048 + tb + row) * 64 + rcol) = vv;
    else if (part == 1)
      *(f16x8*)(Ko + (bh * 2048 + tb + row) * 64 + rcol) = vv;
    else  // row is d, rcol is t-offset
      *(f16x8*)(Vo + (bh * 64 + row) * 2048 + tb + rcol) = vv;
  }
}

// --------------------------- flash attention (1 q-tile / block) -------------
// grid (64 bh, 16 qt-slots); block 256 = 4 waves; wave owns 32 q-rows.
// qt = 15 - blockIdx.y (heavy tiles dispatch first). Block owns the full
// K-range of its q-tile (nt = qt<4 ? 8 : 2(qt+1) k-tiles): fixed-max softmax,
// rsum in-wave -> normalize in-register -> direct f16 Y stores. LDS 33KB ->
// 4 blocks/CU. T5 setprio around MFMA clusters (independent blocks ->
// phase-diverse waves -> scheduler has something to arbitrate; m191 regime).

__global__ __launch_bounds__(256, 4) void k_attn(
    const f16* __restrict__ Q, const f16* __restrict__ Kb,
    const f16* __restrict__ Vt, f16* __restrict__ Y) {
  __shared__ __align__(16) f16 Ks[2][64 * 64];
  __shared__ __align__(16) f16 Vs[2][64 * 64];
  __shared__ float rs[4 * 32];  // per-wave row sums

  const int tid = threadIdx.x;
  const int wave = tid >> 6, lane = tid & 63;
  const int g = lane >> 4, l16 = lane & 15;
  const int bh = blockIdx.x;
  const int b = bh >> 4, h = bh & 15;
  const int qt = 15 - blockIdx.y;
  const int q0 = qt * 128;
  const int nt = (qt < 4) ? 8 : (qt + 1) * 2;  // k-tiles for this q-tile
  const int srowrel = lane >> 3;
  const int sc = (lane & 7) ^ srowrel;  // XOR-swizzled staging chunk

  const f32x4 sinit = {-8.65617025f, -8.65617025f, -8.65617025f, -8.65617025f};

  // Q B-fragments (operand-swapped QK), pre-scaled by log2(e)/8
  f16x8 aq[2][2];
  for (int mi = 0; mi < 2; ++mi) {
    const f16* qrow =
        Q + ((size_t)bh * 2048 + q0 + wave * 32 + mi * 16 + l16) * 64 + g * 8;
    aq[mi][0] = *(const f16x8*)(qrow);
    aq[mi][1] = *(const f16x8*)(qrow + 32);
    for (int kb = 0; kb < 2; ++kb)
      aq[mi][kb] = aq[mi][kb] * (f16)0.18033688f;
  }

  f32x4 o[2][4] = {};       // o[mi][db]: O[m=g*4+r][d=db*16+l16]
  float rsum[2] = {};       // per-lane partial for row m=l16 (quad's k share)

  // prologue: stage tile 0 into buf 0 (each wave: 16 K rows + 16 V rows)
  for (int it = 0; it < 2; ++it) {
    int row = it * 32 + wave * 8 + srowrel;
    gload_lds16(Kb + ((size_t)bh * 2048 + row) * 64 + sc * 8,
                &Ks[0][(it * 32 + wave * 8) * 64]);
    gload_lds16(Vt + ((size_t)bh * 64 + row) * 2048 + sc * 8,
                &Vs[0][(it * 32 + wave * 8) * 64]);
  }
  __syncthreads();

  int cur = 0;
  for (int i = 0; i < nt; ++i) {
    // ---- stage tile i+1 into buf cur^1 (readers joined at barrier i-1) ----
    if (i + 1 < nt) {
      const int kn0 = (i + 1) << 6;
      for (int it = 0; it < 2; ++it) {
        int row = it * 32 + wave * 8 + srowrel;
        gload_lds16(Kb + ((size_t)bh * 2048 + kn0 + row) * 64 + sc * 8,
                    &Ks[cur ^ 1][(it * 32 + wave * 8) * 64]);
        gload_lds16(Vt + ((size_t)bh * 64 + row) * 2048 + kn0 + sc * 8,
                    &Vs[cur ^ 1][(it * 32 + wave * 8) * 64]);
      }
    }

    // ---- compute tile i from buf cur ----
    const int kt0 = i << 6;
    const f16* Kc = Ks[cur];
    const f16* Vc = Vs[cur];

    // T = K Q^T : T[k=g*4+r][m=l16] per nb (k-block), mi (q-block)
    f32x4 t[2][4];
    __builtin_amdgcn_s_setprio(1);
    for (int nb = 0; nb < 4; ++nb) {
      int R = nb * 16 + l16, sw = R & 7;
      f16x8 bk0 = *(const f16x8*)(Kc + R * 64 + ((0 + g) ^ sw) * 8);
      f16x8 bk1 = *(const f16x8*)(Kc + R * 64 + ((4 + g) ^ sw) * 8);
      for (int mi = 0; mi < 2; ++mi) {
        f32x4 acc = MFMA16x32(bk0, aq[mi][0], sinit);
        t[mi][nb] = MFMA16x32(bk1, aq[mi][1], acc);
      }
    }
    __builtin_amdgcn_s_setprio(0);

    // exp -> P stays in registers as 16x16x16 A-frags ap[nb][mi]
    const bool masked = (q0 >= 512) && (kt0 >= q0);
    f16x4 ap[4][2];
    for (int mi = 0; mi < 2; ++mi) {
      const int mrow = q0 + wave * 32 + mi * 16 + l16;
      for (int nb = 0; nb < 4; ++nb)
        for (int r = 0; r < 4; ++r) {
          float pv = __builtin_amdgcn_exp2f(t[mi][nb][r]);
          if (masked && (kt0 + nb * 16 + g * 4 + r > mrow)) pv = 0.f;
          rsum[mi] += pv;
          ap[nb][mi][r] = (f16)pv;
        }
    }

    // O += P V : A = ap (in-register), B = V^T b64 frags from LDS
    __builtin_amdgcn_s_setprio(1);
    for (int db = 0; db < 4; ++db)
      for (int nb = 0; nb < 4; ++nb) {
        int R = db * 16 + l16, sw = R & 7;
        int c = nb * 2 + (g >> 1);
        f16x4 bv = *(const f16x4*)(Vc + R * 64 + (c ^ sw) * 8 + (g & 1) * 4);
        for (int mi = 0; mi < 2; ++mi)
          o[mi][db] = MFMA16x16(ap[nb][mi], bv, o[mi][db]);
      }
    __builtin_amdgcn_s_setprio(0);

    __syncthreads();  // joins all waves' reads of buf cur + drains stages
    cur ^= 1;
  }

  // reduce rsum across quads: all lanes with same l16 get the row total
  for (int mi = 0; mi < 2; ++mi) {
    rsum[mi] += __shfl_xor(rsum[mi], 16, 64);
    rsum[mi] += __shfl_xor(rsum[mi], 32, 64);
  }

  // broadcast row totals to the lanes that hold O rows g*4+r (via LDS)
  if (g == 0)
    for (int mi = 0; mi < 2; ++mi) rs[wave * 32 + mi * 16 + l16] = rsum[mi];
  // same-wave DS write->read: LDS pipe in-order, no barrier needed
  float rinv[2][4];
  for (int mi = 0; mi < 2; ++mi)
    for (int r = 0; r < 4; ++r)
      rinv[mi][r] = 1.0f / rs[wave * 32 + mi * 16 + g * 4 + r];

  // normalize -> f16 -> direct stores (no LDS stage; L2 merges 32B segments)
  const size_t ybase = (size_t)b * 2048 + q0 + wave * 32;
  for (int mi = 0; mi < 2; ++mi)
    for (int db = 0; db < 4; ++db)
      for (int r = 0; r < 4; ++r)
        Y[(ybase + mi * 16 + g * 4 + r) * 1024 + h * 64 + db * 16 + l16] =
            (f16)(o[mi][db][r] * rinv[mi][r]);
}

// --------------------------- GEMM2: y @ W_proj ------------------------------

__global__ __launch_bounds__(256) void k_gemm_proj(
    const f16* __restrict__ A, const f16* __restrict__ Bt,
    const float* __restrict__ bias, float* __restrict__ out) {
  constexpr int KD = 1024;
  __shared__ __align__(16) f16 As[128 * 64];
  __shared__ __align__(16) f16 Bs[128 * 64];
  const int tid = threadIdx.x;
  const int wave = tid >> 6, lane = tid & 63;
  const int g = lane >> 4, l16 = lane & 15;
  const int m0 = blockIdx.y * 128, n0 = blockIdx.x * 128;
  const int wm = (wave >> 1) * 64, wn = (wave & 1) * 64;
  const int srow = wave * 8 + (lane >> 3);
  const int skc = ((lane & 7) ^ (lane >> 3)) * 8;   // pre-swizzled src chunk

  f32x4 acc[4][4] = {};

  for (int k0 = 0; k0 < KD; k0 += 64) {
    __syncthreads();
    for (int it = 0; it < 4; ++it) {
      gload_lds16(A + (size_t)(m0 + it * 32 + srow) * KD + k0 + skc,
                  As + (it * 32 + wave * 8) * 64);
      gload_lds16(Bt + (size_t)(n0 + it * 32 + srow) * KD + k0 + skc,
                  Bs + (it * 32 + wave * 8) * 64);
    }
    __syncthreads();
    for (int kk = 0; kk < 64; kk += 32) {
      const int ks = kk >> 3;
      f16x8 af[4], bf[4];
      for (int mi = 0; mi < 4; ++mi) {
        int R = wm + mi * 16 + l16, sw = R & 7;
        af[mi] = *(const f16x8*)(As + R * 64 + ((ks + g) ^ sw) * 8);
      }
      for (int ni = 0; ni < 4; ++ni) {
        int R = wn + ni * 16 + l16, sw = R & 7;
        bf[ni] = *(const f16x8*)(Bs + R * 64 + ((ks + g) ^ sw) * 8);
      }
      for (int mi = 0; mi < 4; ++mi)
        for (int ni = 0; ni < 4; ++ni)
          acc[mi][ni] = MFMA16x32(af[mi], bf[ni], acc[mi][ni]);
    }
  }

  float bv[4];
  for (int ni = 0; ni < 4; ++ni) bv[ni] = bias[n0 + wn + ni * 16 + l16];

  for (int mi = 0; mi < 4; ++mi)
    for (int ni = 0; ni < 4; ++ni)
      for (int r = 0; r < 4; ++r) {
        int m = m0 + wm + mi * 16 + g * 4 + r;
        int n = n0 + wn + ni * 16 + l16;
        out[(size_t)m * 1024 + n] = acc[mi][ni][r] + bv[ni];
      }
}

// --------------------------- launch ----------------------------------------

extern "C" void kernel_launch(void* const* d_in, const int* in_sizes, int n_in,
                              void* d_out, int out_size, void* d_ws,
                              size_t ws_size, hipStream_t stream) {
  const float* x      = (const float*)d_in[0];
  const float* W_qkv  = (const float*)d_in[1];
  const float* b_qkv  = (const float*)d_in[2];
  const float* W_proj = (const float*)d_in[3];
  const float* b_proj = (const float*)d_in[4];
  float* out = (float*)d_out;

  char* ws = (char*)d_ws;
  f16* xh    = (f16*)ws;   ws += (size_t)8192 * 1024 * 2;   // also reused as Y
  f16* Wqt   = (f16*)ws;   ws += (size_t)3072 * 1024 * 2;
  f16* Wpt   = (f16*)ws;   ws += (size_t)1024 * 1024 * 2;
  f16* Qb    = (f16*)ws;   ws += (size_t)64 * 2048 * 64 * 2;
  f16* Kb    = (f16*)ws;   ws += (size_t)64 * 2048 * 64 * 2;
  f16* Vt    = (f16*)ws;   ws += (size_t)64 * 64 * 2048 * 2;
  f16* Y = xh;  // xh fully consumed by k_gemm_qkv before k_attn writes Y

  k_prep<<<12288, 256, 0, stream>>>(x, xh, W_qkv, Wqt, W_proj, Wpt);
  k_gemm_qkv<<<dim3(24, 64), 256, 0, stream>>>(xh, Wqt, b_qkv, Qb, Kb, Vt);
  k_attn<<<dim3(64, 16), 256, 0, stream>>>(Qb, Kb, Vt, Y);
  k_gemm_proj<<<dim3(8, 64), 256, 0, stream>>>(Y, Wpt, b_proj, out);
}